// Round 1
// baseline (630.296 us; speedup 1.0000x reference)
//
#include <hip/hip_runtime.h>
#include <math.h>

#define Bn 32
#define Nn 2000
#define En 32000
#define Vn 100000
#define Dn 128
#define Rn 39
#define Kn 8

// Workspace layout:
//   cnt : int   [B*N*R]            (per (graph,dst,rel) edge count)
//   a   : float [B*N*K]            (per (graph,src) folded coefficients)
//   ts  : float [B*9*D]            (k=0..7 -> t_k, slot 8 -> sum of x)

__global__ __launch_bounds__(256) void zero_ws(unsigned int* ws, int words) {
    int i = blockIdx.x * blockDim.x + threadIdx.x;
    int stride = gridDim.x * blockDim.x;
    for (; i < words; i += stride) ws[i] = 0u;
}

__global__ __launch_bounds__(256) void hist_kernel(const int* __restrict__ edge_index,
                                                   const int* __restrict__ edge_type,
                                                   int* __restrict__ cnt) {
    int idx = blockIdx.x * blockDim.x + threadIdx.x;
    if (idx >= Bn * En) return;
    int b = idx / En;
    int e = idx - b * En;
    int dst = edge_index[(b * 2 + 1) * En + e];
    int et  = edge_type[idx];
    atomicAdd(&cnt[(b * Nn + dst) * Rn + et], 1);
}

__global__ __launch_bounds__(256) void scatter_a(const int* __restrict__ edge_index,
                                                 const int* __restrict__ edge_type,
                                                 const int* __restrict__ cnt,
                                                 const float* __restrict__ comp,
                                                 float* __restrict__ a) {
    int idx = blockIdx.x * blockDim.x + threadIdx.x;
    if (idx >= Bn * En) return;
    int b = idx / En;
    int e = idx - b * En;
    int src = edge_index[(b * 2 + 0) * En + e];
    int dst = edge_index[(b * 2 + 1) * En + e];
    int et  = edge_type[idx];
    int c = cnt[(b * Nn + dst) * Rn + et];       // >= 1 (this edge is in the bucket)
    float inv = 1.0f / (float)c;
    float* arow = a + (b * Nn + src) * Kn;
    const float* crow = comp + et * Kn;
#pragma unroll
    for (int k = 0; k < Kn; k++) atomicAdd(&arow[k], crow[k] * inv);
}

#define CHUNKS 16
__global__ __launch_bounds__(256) void gather_accum(const int* __restrict__ node_ids,
                                                    const float* __restrict__ emb,
                                                    const float* __restrict__ a,
                                                    float* __restrict__ ts) {
    int b = blockIdx.y;
    int d = threadIdx.x & (Dn - 1);
    int w = threadIdx.x >> 7;                    // 0 or 1: two node-workers per block
    float acc[9];
#pragma unroll
    for (int k = 0; k < 9; k++) acc[k] = 0.0f;
    for (int n = blockIdx.x * 2 + w; n < Nn; n += CHUNKS * 2) {
        int nid = node_ids[b * Nn + n];          // block-uniform -> scalar load
        float v = emb[nid * Dn + d];             // coalesced 512B row
        const float* ar = a + (b * Nn + n) * Kn; // block-uniform row
        acc[8] += v;
#pragma unroll
        for (int k = 0; k < Kn; k++) acc[k] += ar[k] * v;
    }
    float* tsb = ts + b * 9 * Dn;
#pragma unroll
    for (int k = 0; k < 9; k++) atomicAdd(&tsb[k * Dn + d], acc[k]);
}

__global__ __launch_bounds__(128) void finalize(const float* __restrict__ ts,
                                                const float* __restrict__ root,
                                                const float* __restrict__ bases,
                                                const float* __restrict__ bias,
                                                float* __restrict__ out) {
    int b = blockIdx.x;
    int d = threadIdx.x;
    const float* tsb = ts + b * 9 * Dn;
    float g = (float)Nn * bias[d];
    // self/root term: sum_j s[j] * root[j,d]
    for (int j = 0; j < Dn; j++) g += tsb[8 * Dn + j] * root[j * Dn + d];
    // basis terms: sum_k sum_j t_k[j] * bases[k][j,d]
    for (int k = 0; k < Kn; k++) {
        const float* Bk = bases + k * Dn * Dn;
        const float* tk = tsb + k * Dn;
        for (int j = 0; j < Dn; j++) g += tk[j] * Bk[j * Dn + d];
    }
    // L2 norm over the 128-dim vector (2 waves)
    float ss = g * g;
#pragma unroll
    for (int off = 32; off > 0; off >>= 1) ss += __shfl_down(ss, off, 64);
    __shared__ float s2[2];
    if ((threadIdx.x & 63) == 0) s2[threadIdx.x >> 6] = ss;
    __syncthreads();
    float nrm = sqrtf(s2[0] + s2[1]);
    float den = fmaxf(nrm, 1e-5f);
    out[b * Dn + d] = g / den;
}

extern "C" void kernel_launch(void* const* d_in, const int* in_sizes, int n_in,
                              void* d_out, int out_size, void* d_ws, size_t ws_size,
                              hipStream_t stream) {
    const int*   node_ids   = (const int*)d_in[0];
    const int*   edge_index = (const int*)d_in[1];
    const int*   edge_type  = (const int*)d_in[2];
    const float* embedding  = (const float*)d_in[3];
    const float* bases      = (const float*)d_in[4];
    const float* comp       = (const float*)d_in[5];
    const float* root       = (const float*)d_in[6];
    const float* bias       = (const float*)d_in[7];
    float*       out        = (float*)d_out;

    int*   cnt = (int*)d_ws;
    float* a   = (float*)((char*)d_ws + sizeof(int) * (size_t)(Bn * Nn * Rn));
    float* ts  = a + (size_t)Bn * Nn * Kn;

    int words = Bn * Nn * Rn + Bn * Nn * Kn + Bn * 9 * Dn;
    zero_ws<<<2048, 256, 0, stream>>>((unsigned int*)d_ws, words);

    int edgeBlocks = (Bn * En + 255) / 256;
    hist_kernel<<<edgeBlocks, 256, 0, stream>>>(edge_index, edge_type, cnt);
    scatter_a<<<edgeBlocks, 256, 0, stream>>>(edge_index, edge_type, cnt, comp, a);
    gather_accum<<<dim3(CHUNKS, Bn), 256, 0, stream>>>(node_ids, embedding, a, ts);
    finalize<<<Bn, 128, 0, stream>>>(ts, root, bases, bias, out);
}

// Round 2
// 234.729 us; speedup vs baseline: 2.6852x; 2.6852x over previous
//
#include <hip/hip_runtime.h>
#include <math.h>

#define Bn 32
#define Nn 2000
#define En 32000
#define Vn 100000
#define Dn 128
#define Rn 39
#define Kn 8

#define SUBS 8
#define NPS (Nn / SUBS)   // 250 nodes per sub-block
#define CH 32             // gather chunks per graph

// Workspace layout (bytes):
//   [0)              : cnt   int[B*N*R]   = 9,984,000   (dead after K2)
//   [0)              : partial float[B*CH*9*128] = 4,718,592  (aliases cnt, written in K3)
//   [9,984,000)      : a     float[B*N*K] = 2,048,000
// total 12,032,000 bytes

// K1: per (sub,graph) block owns dst-range [s0, s0+250); LDS histogram, direct store.
__global__ __launch_bounds__(1024) void cnt_kernel(const int* __restrict__ edge_index,
                                                   const int* __restrict__ edge_type,
                                                   int* __restrict__ cnt) {
    int sub = blockIdx.x, b = blockIdx.y;
    int s0 = sub * NPS;
    __shared__ int loc[NPS * Rn];                 // 9750 ints = 39 KB
    for (int i = threadIdx.x; i < NPS * Rn; i += 1024) loc[i] = 0;
    __syncthreads();
    const int* dstp = edge_index + (b * 2 + 1) * En;
    const int* etp  = edge_type + b * En;
    for (int e = threadIdx.x; e < En; e += 1024) {
        int du = dstp[e] - s0;
        if ((unsigned)du < NPS) {
            int t = etp[e];
            atomicAdd(&loc[du * Rn + t], 1);      // LDS atomic
        }
    }
    __syncthreads();
    int* g = cnt + (b * Nn + s0) * Rn;
    for (int i = threadIdx.x; i < NPS * Rn; i += 1024) g[i] = loc[i];
}

// K2: per (sub,graph) block owns src-range; a[b,src,k] = sum_e comp[et,k]/cnt[dst,et]
__global__ __launch_bounds__(1024) void a_kernel(const int* __restrict__ edge_index,
                                                 const int* __restrict__ edge_type,
                                                 const int* __restrict__ cnt,
                                                 const float* __restrict__ comp,
                                                 float* __restrict__ a) {
    int sub = blockIdx.x, b = blockIdx.y;
    int s0 = sub * NPS;
    __shared__ float loc[NPS * Kn];               // 2000 floats
    __shared__ float comp_l[Rn * Kn];             // 312 floats
    for (int i = threadIdx.x; i < NPS * Kn; i += 1024) loc[i] = 0.0f;
    for (int i = threadIdx.x; i < Rn * Kn; i += 1024) comp_l[i] = comp[i];
    __syncthreads();
    const int* srcp = edge_index + (b * 2 + 0) * En;
    const int* dstp = edge_index + (b * 2 + 1) * En;
    const int* etp  = edge_type + b * En;
    for (int e = threadIdx.x; e < En; e += 1024) {
        int su = srcp[e] - s0;
        if ((unsigned)su < NPS) {
            int dst = dstp[e];
            int t   = etp[e];
            float inv = 1.0f / (float)cnt[(b * Nn + dst) * Rn + t];
            float* lrow = &loc[su * Kn];
            const float* crow = &comp_l[t * Kn];
#pragma unroll
            for (int k = 0; k < Kn; k++) atomicAdd(&lrow[k], crow[k] * inv);  // LDS atomic
        }
    }
    __syncthreads();
    float* g = a + (b * Nn + s0) * Kn;
    for (int i = threadIdx.x; i < NPS * Kn; i += 1024) g[i] = loc[i];
}

// K3: gather embedding rows once per (graph,node); 9 register accumulators;
// block-local LDS combine; non-atomic partial store per chunk.
__global__ __launch_bounds__(256) void gather_kernel(const int* __restrict__ node_ids,
                                                     const float* __restrict__ emb,
                                                     const float* __restrict__ a,
                                                     float* __restrict__ partial) {
    int c = blockIdx.x, b = blockIdx.y;
    int d = threadIdx.x & (Dn - 1);
    int w = threadIdx.x >> 7;                     // 2 node-workers per block
    float acc[9];
#pragma unroll
    for (int k = 0; k < 9; k++) acc[k] = 0.0f;
    for (int n = c * 2 + w; n < Nn; n += CH * 2) {
        int nid = node_ids[b * Nn + n];
        float v = emb[(size_t)nid * Dn + d];      // coalesced 512B row
        const float4* ar = (const float4*)(a + (size_t)(b * Nn + n) * Kn);
        float4 a0 = ar[0], a1 = ar[1];            // uniform address -> broadcast
        acc[8] += v;
        acc[0] += a0.x * v; acc[1] += a0.y * v; acc[2] += a0.z * v; acc[3] += a0.w * v;
        acc[4] += a1.x * v; acc[5] += a1.y * v; acc[6] += a1.z * v; acc[7] += a1.w * v;
    }
    __shared__ float red[9 * Dn];
    if (w == 0) {
#pragma unroll
        for (int k = 0; k < 9; k++) red[k * Dn + d] = acc[k];
    }
    __syncthreads();
    if (w == 1) {
#pragma unroll
        for (int k = 0; k < 9; k++) red[k * Dn + d] += acc[k];
    }
    __syncthreads();
    float* g = partial + ((size_t)b * CH + c) * 9 * Dn;
    for (int i = threadIdx.x; i < 9 * Dn; i += 256) g[i] = red[i];
}

// K4: reduce chunk partials, 9x(128x128) matvec, L2-normalize.
__global__ __launch_bounds__(128) void final_kernel(const float* __restrict__ partial,
                                                    const float* __restrict__ root,
                                                    const float* __restrict__ bases,
                                                    const float* __restrict__ bias,
                                                    float* __restrict__ out) {
    int b = blockIdx.x;
    int d = threadIdx.x;
    __shared__ float ts[9 * Dn];
    for (int i = d; i < 9 * Dn; i += Dn) {
        float s = 0.0f;
        const float* p = partial + (size_t)b * CH * 9 * Dn + i;
        for (int c = 0; c < CH; c++) s += p[c * 9 * Dn];
        ts[i] = s;
    }
    __syncthreads();
    float g = (float)Nn * bias[d];
    const float* sv = &ts[8 * Dn];
    for (int j = 0; j < Dn; j++) g += sv[j] * root[j * Dn + d];
    for (int k = 0; k < Kn; k++) {
        const float* Bk = bases + (size_t)k * Dn * Dn;
        const float* tk = &ts[k * Dn];
        for (int j = 0; j < Dn; j++) g += tk[j] * Bk[j * Dn + d];
    }
    float ss = g * g;
#pragma unroll
    for (int off = 32; off > 0; off >>= 1) ss += __shfl_down(ss, off, 64);
    __shared__ float s2[2];
    if ((threadIdx.x & 63) == 0) s2[threadIdx.x >> 6] = ss;
    __syncthreads();
    float nrm = sqrtf(s2[0] + s2[1]);
    out[b * Dn + d] = g / fmaxf(nrm, 1e-5f);
}

extern "C" void kernel_launch(void* const* d_in, const int* in_sizes, int n_in,
                              void* d_out, int out_size, void* d_ws, size_t ws_size,
                              hipStream_t stream) {
    const int*   node_ids   = (const int*)d_in[0];
    const int*   edge_index = (const int*)d_in[1];
    const int*   edge_type  = (const int*)d_in[2];
    const float* embedding  = (const float*)d_in[3];
    const float* bases      = (const float*)d_in[4];
    const float* comp       = (const float*)d_in[5];
    const float* root       = (const float*)d_in[6];
    const float* bias       = (const float*)d_in[7];
    float*       out        = (float*)d_out;

    int*   cnt     = (int*)d_ws;                                  // dead after K2
    float* partial = (float*)d_ws;                                // aliases cnt (K3+)
    float* a       = (float*)((char*)d_ws + (size_t)Bn * Nn * Rn * sizeof(int));

    cnt_kernel   <<<dim3(SUBS, Bn), 1024, 0, stream>>>(edge_index, edge_type, cnt);
    a_kernel     <<<dim3(SUBS, Bn), 1024, 0, stream>>>(edge_index, edge_type, cnt, comp, a);
    gather_kernel<<<dim3(CH, Bn),   256,  0, stream>>>(node_ids, embedding, a, partial);
    final_kernel <<<Bn, Dn, 0, stream>>>(partial, root, bases, bias, out);
}

// Round 3
// 221.837 us; speedup vs baseline: 2.8413x; 1.0581x over previous
//
#include <hip/hip_runtime.h>
#include <math.h>

#define Bn 32
#define Nn 2000
#define En 32000
#define Vn 100000
#define Dn 128
#define Rn 39
#define Kn 8

#define SUBS 8
#define NPS (Nn / SUBS)   // 250 nodes per sub-block
#define CH 64             // gather chunks per graph

// Workspace layout (bytes):
//   [0)         : cnt     int  [B*N*R]        = 9,984,000  (dead after K2)
//   [0)         : partial float[B*CH*9*128]   = 9,437,184  (aliases cnt, written in K3)
//   [9,984,000) : a       float[B*N*K]        = 2,048,000
// total 12,032,000 bytes
//
// Grid swizzle: grids are (Bn, SUBS/CH) so all blocks of graph b share
// linear id == b (mod 8) -> same XCD under round-robin dispatch -> the
// graph's edge data / cnt tile stays in that XCD's 4 MB L2 (R1 showed 8x
// HBM fetch amplification with the transposed grid).

// K1: per (graph,sub) block owns dst-range [s0, s0+250); LDS histogram, direct store.
__global__ __launch_bounds__(1024) void cnt_kernel(const int* __restrict__ edge_index,
                                                   const int* __restrict__ edge_type,
                                                   int* __restrict__ cnt) {
    int b = blockIdx.x, sub = blockIdx.y;
    int s0 = sub * NPS;
    __shared__ int loc[NPS * Rn];                 // 9750 ints = 39 KB
    for (int i = threadIdx.x; i < NPS * Rn; i += 1024) loc[i] = 0;
    __syncthreads();
    const int* dstp = edge_index + (b * 2 + 1) * En;
    const int* etp  = edge_type + b * En;
    for (int e = threadIdx.x; e < En; e += 1024) {
        int du = dstp[e] - s0;
        if ((unsigned)du < NPS) {
            atomicAdd(&loc[du * Rn + etp[e]], 1); // LDS atomic
        }
    }
    __syncthreads();
    int* g = cnt + (b * Nn + s0) * Rn;
    for (int i = threadIdx.x; i < NPS * Rn; i += 1024) g[i] = loc[i];
}

// K2: per (graph,sub) block owns src-range; a[b,src,k] = sum_e comp[et,k]/cnt[dst,et]
__global__ __launch_bounds__(1024) void a_kernel(const int* __restrict__ edge_index,
                                                 const int* __restrict__ edge_type,
                                                 const int* __restrict__ cnt,
                                                 const float* __restrict__ comp,
                                                 float* __restrict__ a) {
    int b = blockIdx.x, sub = blockIdx.y;
    int s0 = sub * NPS;
    __shared__ float loc[NPS * Kn];               // 8 KB
    __shared__ float comp_l[Rn * Kn];
    for (int i = threadIdx.x; i < NPS * Kn; i += 1024) loc[i] = 0.0f;
    for (int i = threadIdx.x; i < Rn * Kn; i += 1024) comp_l[i] = comp[i];
    __syncthreads();
    const int* srcp = edge_index + (b * 2 + 0) * En;
    const int* dstp = edge_index + (b * 2 + 1) * En;
    const int* etp  = edge_type + b * En;
    for (int e = threadIdx.x; e < En; e += 1024) {
        int su = srcp[e] - s0;
        if ((unsigned)su < NPS) {
            int dst = dstp[e];
            int t   = etp[e];
            float inv = 1.0f / (float)cnt[(b * Nn + dst) * Rn + t];
            float* lrow = &loc[su * Kn];
            const float* crow = &comp_l[t * Kn];
#pragma unroll
            for (int k = 0; k < Kn; k++) atomicAdd(&lrow[k], crow[k] * inv);  // LDS atomic
        }
    }
    __syncthreads();
    float* g = a + (b * Nn + s0) * Kn;
    for (int i = threadIdx.x; i < NPS * Kn; i += 1024) g[i] = loc[i];
}

// K3: gather embedding rows; 9 register accumulators; block-local LDS combine;
// non-atomic partial store per chunk.
__global__ __launch_bounds__(256) void gather_kernel(const int* __restrict__ node_ids,
                                                     const float* __restrict__ emb,
                                                     const float* __restrict__ a,
                                                     float* __restrict__ partial) {
    int b = blockIdx.x, c = blockIdx.y;
    int d = threadIdx.x & (Dn - 1);
    int w = threadIdx.x >> 7;                     // 2 node-workers per block
    float acc[9];
#pragma unroll
    for (int k = 0; k < 9; k++) acc[k] = 0.0f;
    for (int n = c * 2 + w; n < Nn; n += CH * 2) {
        int nid = node_ids[b * Nn + n];
        float v = emb[(size_t)nid * Dn + d];      // coalesced 512B row
        const float4* ar = (const float4*)(a + (size_t)(b * Nn + n) * Kn);
        float4 a0 = ar[0], a1 = ar[1];
        acc[8] += v;
        acc[0] += a0.x * v; acc[1] += a0.y * v; acc[2] += a0.z * v; acc[3] += a0.w * v;
        acc[4] += a1.x * v; acc[5] += a1.y * v; acc[6] += a1.z * v; acc[7] += a1.w * v;
    }
    __shared__ float red[9 * Dn];
    if (w == 0) {
#pragma unroll
        for (int k = 0; k < 9; k++) red[k * Dn + d] = acc[k];
    }
    __syncthreads();
    if (w == 1) {
#pragma unroll
        for (int k = 0; k < 9; k++) red[k * Dn + d] += acc[k];
    }
    __syncthreads();
    float* g = partial + ((size_t)b * CH + c) * 9 * Dn;
    for (int i = threadIdx.x; i < 9 * Dn; i += 256) g[i] = red[i];
}

// K4: reduce chunk partials, 9x(128x128) matvec split across 2 thread-halves,
// L2-normalize.
__global__ __launch_bounds__(256) void final_kernel(const float* __restrict__ partial,
                                                    const float* __restrict__ root,
                                                    const float* __restrict__ bases,
                                                    const float* __restrict__ bias,
                                                    float* __restrict__ out) {
    int b = blockIdx.x;
    int d = threadIdx.x & (Dn - 1);
    int h = threadIdx.x >> 7;                     // 0 or 1
    __shared__ float ts[9 * Dn];
    for (int i = threadIdx.x; i < 9 * Dn; i += 256) {
        float s = 0.0f;
        const float* p = partial + (size_t)b * CH * 9 * Dn + i;
        for (int c = 0; c < CH; c++) s += p[c * 9 * Dn];
        ts[i] = s;
    }
    __syncthreads();
    float gp = 0.0f;
    if (h == 0) {
        const float* sv = &ts[8 * Dn];
        for (int j = 0; j < Dn; j++) gp += sv[j] * root[j * Dn + d];
        for (int k = 0; k < 4; k++) {
            const float* Bk = bases + (size_t)k * Dn * Dn;
            const float* tk = &ts[k * Dn];
            for (int j = 0; j < Dn; j++) gp += tk[j] * Bk[j * Dn + d];
        }
    } else {
        for (int k = 4; k < Kn; k++) {
            const float* Bk = bases + (size_t)k * Dn * Dn;
            const float* tk = &ts[k * Dn];
            for (int j = 0; j < Dn; j++) gp += tk[j] * Bk[j * Dn + d];
        }
    }
    __shared__ float gsh[2][Dn];
    gsh[h][d] = gp;
    __syncthreads();
    float g = 0.0f;
    if (h == 0) g = (float)Nn * bias[d] + gsh[0][d] + gsh[1][d];
    float ss = g * g;                              // h==1 lanes contribute 0
#pragma unroll
    for (int off = 32; off > 0; off >>= 1) ss += __shfl_down(ss, off, 64);
    __shared__ float s4[4];
    if ((threadIdx.x & 63) == 0) s4[threadIdx.x >> 6] = ss;
    __syncthreads();
    float nrm = sqrtf(s4[0] + s4[1] + s4[2] + s4[3]);
    if (h == 0) out[b * Dn + d] = g / fmaxf(nrm, 1e-5f);
}

extern "C" void kernel_launch(void* const* d_in, const int* in_sizes, int n_in,
                              void* d_out, int out_size, void* d_ws, size_t ws_size,
                              hipStream_t stream) {
    const int*   node_ids   = (const int*)d_in[0];
    const int*   edge_index = (const int*)d_in[1];
    const int*   edge_type  = (const int*)d_in[2];
    const float* embedding  = (const float*)d_in[3];
    const float* bases      = (const float*)d_in[4];
    const float* comp       = (const float*)d_in[5];
    const float* root       = (const float*)d_in[6];
    const float* bias       = (const float*)d_in[7];
    float*       out        = (float*)d_out;

    int*   cnt     = (int*)d_ws;                                  // dead after K2
    float* partial = (float*)d_ws;                                // aliases cnt (K3+)
    float* a       = (float*)((char*)d_ws + (size_t)Bn * Nn * Rn * sizeof(int));

    cnt_kernel   <<<dim3(Bn, SUBS), 1024, 0, stream>>>(edge_index, edge_type, cnt);
    a_kernel     <<<dim3(Bn, SUBS), 1024, 0, stream>>>(edge_index, edge_type, cnt, comp, a);
    gather_kernel<<<dim3(Bn, CH),   256,  0, stream>>>(node_ids, embedding, a, partial);
    final_kernel <<<Bn, 256, 0, stream>>>(partial, root, bases, bias, out);
}